// Round 12
// baseline (313.738 us; speedup 1.0000x reference)
//
#include <hip/hip_runtime.h>

typedef _Float16 f16;
typedef __attribute__((ext_vector_type(8))) _Float16 f16x8;
typedef __attribute__((ext_vector_type(4))) _Float16 f16x4;
typedef __attribute__((ext_vector_type(4))) float f32x4;

#define BATCH 16
#define NSEQ  2048
#define DDIM  300
#define DPK   328   // padded row length (f16) for row-major Xf/Yf (zeros in [300,328))
#define DPV   304   // padded d-rows for transposed XT/YT (zeros in [300,304))
#define NTP   2056  // padded q-cols for transposed copies (zeros in [2048,2056))
#define XF_ELEMS (BATCH*NSEQ*DPK)
#define XT_ELEMS (BATCH*DPV*NTP)

__device__ __forceinline__ void gl_lds16(const void* g, void* l) {
  __builtin_amdgcn_global_load_lds((const __attribute__((address_space(1))) unsigned int*)g,
                                   (__attribute__((address_space(3))) unsigned int*)l, 16, 0, 0);
}

// ---------------------------------------------------------------------------
// Preprocess: X,Y f32 -> f16 row-major (padded) + f16 transposed (padded)
// ---------------------------------------------------------------------------
__global__ __launch_bounds__(256) void prep_kernel(const float* __restrict__ X,
                                                   const float* __restrict__ Y,
                                                   f16* __restrict__ Xf, f16* __restrict__ Yf,
                                                   f16* __restrict__ XT, f16* __restrict__ YT) {
  __shared__ float tile[32][33];
  int bz   = blockIdx.z;            // 0..31 = tensor*16 + b
  int tsel = bz >> 4, b = bz & 15;
  const float* src = tsel ? Y : X;
  f16* dF = tsel ? Yf : Xf;
  f16* dT = tsel ? YT : XT;
  int d0 = blockIdx.y * 32;
  int q0 = blockIdx.x * 32;
  int tid = threadIdx.x;
  int c = tid & 31, rr = tid >> 5;

  #pragma unroll
  for (int i = 0; i < 4; ++i) {
    int qr = rr + i * 8;
    int q = q0 + qr, d = d0 + c;
    float v = 0.f;
    if (q < NSEQ && d < DDIM) v = src[(size_t)b * NSEQ * DDIM + (size_t)q * DDIM + d];
    tile[c][qr] = v;
    if (q < NSEQ && d < DPK) dF[(size_t)b * NSEQ * DPK + (size_t)q * DPK + d] = (f16)v;
  }
  __syncthreads();
  #pragma unroll
  for (int i = 0; i < 4; ++i) {
    int dr = rr + i * 8;
    int d = d0 + dr, q = q0 + c;
    if (d < DPV && q < NTP) dT[(size_t)b * DPV * NTP + (size_t)d * NTP + q] = (f16)tile[dr][c];
  }
}

// ---------------------------------------------------------------------------
// Flash attention v12 = R9's pipelined K/V-double-buffered kernel with the
// serial chain restructured. Occupancy is hard-capped at 8 waves/CU (arch
// VGPR 108 + ~130 accum ≈ 240/wave -> 2 waves/SIMD; rocprof VGPR_Count is
// arch-only) — so this round shortens the exposed critical path instead:
//  * PV[t-1] moved AFTER the max-shuffle + Mx-write: 20 MFMAs now hide the
//    shfl chain, Mx LDS latency, and B1 arrival skew.
//  * lsum per-tile shuffles removed: per-lane partials (rescaled by al like
//    O), single shfl-reduce in the epilogue (-4 ds_bpermute/tile).
// Iter t: QK^T[t] -> stage K[t+1],V[t] -> shfl-max + Mx write -> PV[t-1]
// -> B1(lgkm) -> combine max/defer-rescale/exp/P-write -> B2(lgkm+vmcnt(0),
// drains stages issued ~2500 cyc earlier). Epilogue: PV[63].
// 8 waves = 4 qg x 2 members, QBLK=128, KV tile 32, kv-split QK^T + d-split
// PV. LDS 101376 B. Grid 512, XCD-chunk swizzled. __launch_bounds__(512,1).
// ---------------------------------------------------------------------------
__global__ __launch_bounds__(512, 1) void attn_kernel(const f16* __restrict__ Xf,
                                                      const f16* __restrict__ Yf,
                                                      const f16* __restrict__ XT,
                                                      const f16* __restrict__ YT,
                                                      float* __restrict__ out) {
  __shared__ __align__(16) f16 Ksh[2][32][DPK];   // 41984 B (656 B rows)
  __shared__ __align__(16) f16 VTsh[2][DPV][40];  // 48640 B (80 B rows)
  __shared__ __align__(16) f16 Psh[4][32][40];    // 10240 B per-qg P
  __shared__ float2 Mx[4][2][16];                 //   512 B max/lsum exchange
                                                  // total 101376 B

  int idx = blockIdx.x;
  int swz = (idx & 7) * 64 + (idx >> 3);          // 512 % 8 == 0: bijective XCD chunking
  int qt  = swz & 15;
  int b   = (swz >> 4) & 15;
  int dir = swz >> 8;

  const f16* Qsrc = dir ? Yf : Xf;
  const f16* Ksrc = dir ? Xf : Yf;
  const f16* Vts  = dir ? XT : YT;   // V^T source [DPV][NTP]

  const size_t bq = (size_t)b * NSEQ * DPK;
  const size_t bt = (size_t)b * DPV * NTP;

  int tid = threadIdx.x;
  int lane = tid & 63, wid = tid >> 6;
  int qg = wid >> 1, mem = wid & 1;
  int l15 = lane & 15, g = lane >> 4;
  int qbase = qt * 128 + qg * 32;     // q-group's 32 rows (shared by both members)

  // Q fragments (both members hold qg's 32 q): lane = Q[q=qi*16+l15][ks*32+g*8+j]
  f16x8 qf[2][10];
  #pragma unroll
  for (int qi = 0; qi < 2; ++qi) {
    const f16* qrow = Qsrc + bq + (size_t)(qbase + qi * 16 + l15) * DPK + g * 8;
    #pragma unroll
    for (int ks = 0; ks < 10; ++ks) qf[qi][ks] = *(const f16x8*)(qrow + ks * 32);
  }

  const int dtoff = mem ? 10 : 0;     // PV d-tiles: member0 d 0..159, member1 160..303
  const int ndt   = mem ? 9 : 10;

  f32x4 O[10][2];
  #pragma unroll
  for (int dt = 0; dt < 10; ++dt) {
    O[dt][0] = (f32x4){0.f, 0.f, 0.f, 0.f};
    O[dt][1] = (f32x4){0.f, 0.f, 0.f, 0.f};
  }
  float m0 = -3.0e38f, m1 = -3.0e38f;
  float l0 = 0.f, l1 = 0.f;           // per-LANE partial sums (reduced in epilogue)

  const char* gK0 = (const char*)(Ksrc + bq);
  const char* gV0 = (const char*)(Vts + bt);

  auto stageK = [&](int tt, int buf) {
    const char* gK = gK0 + (size_t)tt * (32 * DPK * 2);
    char* lK = (char*)&Ksh[buf][0][0];
    #pragma unroll
    for (int i = 0; i < 3; ++i) {          // 1312 chunks of 16 B
      int c = i * 512 + tid;
      if (c < 1312) gl_lds16(gK + c * 16, lK + c * 16);
    }
  };
  auto stageV = [&](int tt, int buf) {
    const char* gV = gV0 + (size_t)tt * 64;
    char* lV = (char*)&VTsh[buf][0][0];
    #pragma unroll
    for (int i = 0; i < 3; ++i) {          // 304 rows x 5 slots (64 B data + 16 B pad read)
      int c = i * 512 + tid;
      if (c < 1520) {
        int row = c / 5, slot = c - row * 5;
        gl_lds16(gV + (size_t)row * (NTP * 2) + slot * 16, lV + c * 16);
      }
    }
  };

  stageK(0, 0);                             // K[0] -> buf0
  asm volatile("s_waitcnt vmcnt(0)" ::: "memory");
  __builtin_amdgcn_s_barrier();
  __builtin_amdgcn_sched_barrier(0);

  #pragma unroll 1
  for (int t = 0; t < 64; ++t) {
    int kcur = t & 1;                       // K[t] buffer
    int vprev = (t - 1) & 1;                // V[t-1] buffer (valid for t>0)

    // ---- Phase A: QK^T[t] — S^T[own 16-kv half][qg's 32 q]
    f32x4 S0 = (f32x4){0.f,0.f,0.f,0.f}, S1 = (f32x4){0.f,0.f,0.f,0.f};
    __builtin_amdgcn_s_setprio(1);
    #pragma unroll
    for (int ks = 0; ks < 10; ++ks) {
      f16x8 a = *(const f16x8*)&Ksh[kcur][mem * 16 + l15][ks * 32 + g * 8];
      S0 = __builtin_amdgcn_mfma_f32_16x16x32_f16(a, qf[0][ks], S0, 0, 0, 0);
      S1 = __builtin_amdgcn_mfma_f32_16x16x32_f16(a, qf[1][ks], S1, 0, 0, 0);
    }
    __builtin_amdgcn_s_setprio(0);

    // ---- Phase B: stage K[t+1], V[t] (WAR-safe: those buffers' last readers
    //      finished before B2[t-1]); drained at B2[t], ~2500 cyc later.
    if (t < 63) stageK(t + 1, kcur ^ 1);
    stageV(t, kcur);

    // ---- Phase C: partial max over own 16 kv + Mx write
    float p0 = fmaxf(fmaxf(S0[0], S0[1]), fmaxf(S0[2], S0[3]));
    float p1 = fmaxf(fmaxf(S1[0], S1[1]), fmaxf(S1[2], S1[3]));
    p0 = fmaxf(p0, __shfl_xor(p0, 16, 64)); p0 = fmaxf(p0, __shfl_xor(p0, 32, 64));
    p1 = fmaxf(p1, __shfl_xor(p1, 16, 64)); p1 = fmaxf(p1, __shfl_xor(p1, 32, 64));
    if (g == 0) Mx[qg][mem][l15] = float2{p0, p1};

    // ---- Phase D: PV[t-1] — hides the shfl chain, Mx latency, B1 skew
    if (t > 0) {
      f16x8 pb0 = *(const f16x8*)&Psh[qg][l15][g * 8];
      f16x8 pb1 = *(const f16x8*)&Psh[qg][16 + l15][g * 8];
      __builtin_amdgcn_s_setprio(1);
      #pragma unroll
      for (int dt = 0; dt < 10; ++dt) {
        if (dt < ndt) {
          f16x8 vf = *(const f16x8*)&VTsh[vprev][(dtoff + dt) * 16 + l15][g * 8];
          O[dt][0] = __builtin_amdgcn_mfma_f32_16x16x32_f16(vf, pb0, O[dt][0], 0, 0, 0);
          O[dt][1] = __builtin_amdgcn_mfma_f32_16x16x32_f16(vf, pb1, O[dt][1], 0, 0, 0);
        }
      }
      __builtin_amdgcn_s_setprio(0);
    }

    // ---- B1: Mx visible; PV[t-1]'s Psh/VTsh reads complete (WAR for below)
    asm volatile("s_waitcnt lgkmcnt(0)" ::: "memory");
    __builtin_amdgcn_s_barrier();
    __builtin_amdgcn_sched_barrier(0);

    // ---- Phase E: combine maxes, defer-max rescale, exp, P-write, partials
    float2 pp = Mx[qg][mem ^ 1][l15];
    float tm0 = fmaxf(p0, pp.x), tm1 = fmaxf(p1, pp.y);

    if (__any(tm0 > m0 + 8.0f)) {          // defer-max (identical in both members)
      float mn = fmaxf(m0, tm0), al = __expf(m0 - mn);
      l0 *= al;
      #pragma unroll
      for (int dt = 0; dt < 10; ++dt) {
        O[dt][0][0] *= al; O[dt][0][1] *= al; O[dt][0][2] *= al; O[dt][0][3] *= al;
      }
      m0 = mn;
    }
    if (__any(tm1 > m1 + 8.0f)) {
      float mn = fmaxf(m1, tm1), al = __expf(m1 - mn);
      l1 *= al;
      #pragma unroll
      for (int dt = 0; dt < 10; ++dt) {
        O[dt][1][0] *= al; O[dt][1][1] *= al; O[dt][1][2] *= al; O[dt][1][3] *= al;
      }
      m1 = mn;
    }

    f16x4 h0, h1;
    #pragma unroll
    for (int r = 0; r < 4; ++r) {
      float e0 = __expf(S0[r] - m0);       // bounded by e^8
      float e1 = __expf(S1[r] - m1);
      h0[r] = (f16)e0; h1[r] = (f16)e1;
      l0 += e0; l1 += e1;                  // per-lane partials; no shfl here
    }
    *(f16x4*)&Psh[qg][l15][mem * 16 + g * 4]      = h0;   // qi=0 rows
    *(f16x4*)&Psh[qg][16 + l15][mem * 16 + g * 4] = h1;   // qi=1 rows

    // ---- B2: P[t] visible + drain K[t+1],V[t] staging (issued in phase B)
    asm volatile("s_waitcnt lgkmcnt(0) vmcnt(0)" ::: "memory");
    __builtin_amdgcn_s_barrier();
    __builtin_amdgcn_sched_barrier(0);
  }

  // ---- Epilogue PV[63] (trailing tile of the pipeline)
  {
    int vprev = 63 & 1;
    f16x8 pb0 = *(const f16x8*)&Psh[qg][l15][g * 8];
    f16x8 pb1 = *(const f16x8*)&Psh[qg][16 + l15][g * 8];
    __builtin_amdgcn_s_setprio(1);
    #pragma unroll
    for (int dt = 0; dt < 10; ++dt) {
      if (dt < ndt) {
        f16x8 vf = *(const f16x8*)&VTsh[vprev][(dtoff + dt) * 16 + l15][g * 8];
        O[dt][0] = __builtin_amdgcn_mfma_f32_16x16x32_f16(vf, pb0, O[dt][0], 0, 0, 0);
        O[dt][1] = __builtin_amdgcn_mfma_f32_16x16x32_f16(vf, pb1, O[dt][1], 0, 0, 0);
      }
    }
    __builtin_amdgcn_s_setprio(0);
  }

  // ---- reduce per-lane partials across g, exchange with partner member
  l0 += __shfl_xor(l0, 16, 64); l0 += __shfl_xor(l0, 32, 64);
  l1 += __shfl_xor(l1, 16, 64); l1 += __shfl_xor(l1, 32, 64);
  if (g == 0) Mx[qg][mem][l15] = float2{l0, l1};
  asm volatile("s_waitcnt lgkmcnt(0)" ::: "memory");
  __builtin_amdgcn_s_barrier();
  __builtin_amdgcn_sched_barrier(0);
  float2 pl = Mx[qg][mem ^ 1][l15];
  float r0 = 1.0f / (l0 + pl.x);
  float r1 = 1.0f / (l1 + pl.y);

  #pragma unroll
  for (int qi = 0; qi < 2; ++qi) {
    float rinv = qi ? r1 : r0;
    int q = qbase + qi * 16 + l15;
    const f16* mrow = Qsrc + bq + (size_t)q * DPK;
    size_t orow = (size_t)b * (4096 * 300) + (size_t)(dir * 2048 + q) * 300;
    #pragma unroll
    for (int dt = 0; dt < 10; ++dt) {
      if (dt < ndt) {
        int d = (dtoff + dt) * 16 + g * 4;
        if (d < 300) {
          f16x4 mu = *(const f16x4*)(mrow + d);
          f32x4 o;
          o[0] = O[dt][qi][0] * rinv * (float)mu[0];
          o[1] = O[dt][qi][1] * rinv * (float)mu[1];
          o[2] = O[dt][qi][2] * rinv * (float)mu[2];
          o[3] = O[dt][qi][3] * rinv * (float)mu[3];
          *(f32x4*)&out[orow + d] = o;
        }
      }
    }
  }
}

extern "C" void kernel_launch(void* const* d_in, const int* in_sizes, int n_in,
                              void* d_out, int out_size, void* d_ws, size_t ws_size,
                              hipStream_t stream) {
  const float* X = (const float*)d_in[0];
  const float* Y = (const float*)d_in[1];
  float* out = (float*)d_out;

  size_t need = (size_t)(2 * XF_ELEMS + 2 * XT_ELEMS) * sizeof(f16);  // ~83 MB
  if (ws_size < need) return;

  f16* Xf = (f16*)d_ws;
  f16* Yf = Xf + XF_ELEMS;
  f16* XT = Yf + XF_ELEMS;
  f16* YT = XT + XT_ELEMS;

  prep_kernel<<<dim3(65, 11, 32), 256, 0, stream>>>(X, Y, Xf, Yf, XT, YT);
  attn_kernel<<<dim3(512), 512, 0, stream>>>(Xf, Yf, XT, YT, out);
}